// Round 6
// baseline (180.133 us; speedup 1.0000x reference)
//
#include <hip/hip_runtime.h>
#include <math.h>

// Problem constants: bases [1,4,136,200] f32, box_feat [N,789] f32
// (col0 = image idx, 1:5 = box, 5: = 4*14*14 coeffs), out [N,544,800] f32.
#define OUTD 56
#define COD  14
#define BH   136
#define BW   200
#define IMGH 544
#define IMGW 800
#define BB   4
#define BFS  789      // 5 + 4*14*14
#define RPB  8        // output rows per band
#define W4   (IMGW / 4)
#define MAXMR 16      // mask rows per 8-row band: box >= 32px -> invh <= 1.75
#define MAXCH 29      // band-chunks covering max interior row span (~225 rows)

typedef float f4 __attribute__((ext_vector_type(4)));

// ---------------------------------------------------------------------------
// Interior-only paste. Zeros are written by a hipMemsetAsync graph node
// (the runtime's fillBufferAligned path, measured at 6.6 TB/s in this exact
// graph — our own kernels' store streams only sustain ~2.5-3 TB/s across 5
// structural variants, mechanism unidentified).
// Block = (band-chunk j, roi n): h0 = h_lo(n) + j*8. Blocks past the box's
// row range exit immediately (block-uniform). Interior bands recompute their
// <=16 needed 56-wide mask rows into LDS (R4's verified math), then paste
// only the f4 columns inside the box's x-support. Everything outside the
// outward-rounded support is already zero from the memset.
// ---------------------------------------------------------------------------
__global__ __launch_bounds__(128) void interior_kernel(
    const float* __restrict__ bases,
    const float* __restrict__ box_feat,
    f4* __restrict__ out) {
  const int n   = blockIdx.y;
  const int tid = threadIdx.x;

  const float* bf = box_feat + (size_t)n * BFS;
  const float x0 = bf[1], y0v = bf[2], x1 = bf[3], y1v = bf[4];

  const float invh = (float)OUTD / (y1v - y0v);
  const float cyo  = (0.5f - y0v) * invh - 0.5f;   // fy(h) = h*invh + cyo
  const float invw = (float)OUTD / (x1 - x0);
  const float cxo  = (0.5f - x0) * invw - 0.5f;    // fx(q) = q*invw + cxo

  // interior row range, rounded outward (anything outside evaluates to 0)
  int h_lo = (int)floorf((-1.0f - cyo) / invh) - 1;
  if (h_lo < 0) h_lo = 0;
  int h_hi = (int)ceilf(((float)OUTD - cyo) / invh) + 2;
  if (h_hi > IMGH) h_hi = IMGH;

  const int h0 = h_lo + blockIdx.x * RPB;
  if (h0 >= h_hi) return;                          // block-uniform

  // interior col range (f4 granularity), rounded outward
  int q_lo = (int)floorf((-1.0f - cxo) / invw) - 1;
  if (q_lo < 0) q_lo = 0;
  int q_hi = (int)ceilf(((float)OUTD - cxo) / invw) + 2;
  if (q_hi > IMGW) q_hi = IMGW;
  const int q4_lo = q_lo >> 2;
  const int q4_hi = (q_hi + 3) >> 2;               // exclusive

  // mask rows needed by this band (outward-safe, <= MAXMR)
  const float fy_lo = fmaf((float)h0, invh, cyo);
  const float fy_hi = fmaf((float)(h0 + RPB - 1), invh, cyo);
  int rlo = (int)floorf(fy_lo);
  rlo = rlo < 0 ? 0 : (rlo > OUTD - 1 ? OUTD - 1 : rlo);
  int rhi = (int)floorf(fy_hi) + 1;
  rhi = rhi < 0 ? 0 : (rhi > OUTD - 1 ? OUTD - 1 : rhi);
  const int nrows = rhi - rlo + 1;                 // 1 .. MAXMR

  __shared__ float mrows[MAXMR][OUTD];

  // ---- mask eval into LDS (identical math to prior rounds) ----
  {
    const int bidx = (int)bf[0];
    const float* feat = bases + (size_t)bidx * BB * BH * BW;
    const float* top  = bf + 5;
    const float sx0 = x0 * 0.25f - 0.5f;
    const float sy0 = y0v * 0.25f - 0.5f;
    const float bwv = (x1 - x0) * 0.25f * (1.0f / OUTD);
    const float bhv = (y1v - y0v) * 0.25f * (1.0f / OUTD);
    const int nev = nrows * OUTD;

    for (int idx = tid; idx < nev; idx += 128) {
      const int rr = idx / OUTD;                   // const div -> magic mul
      const int x  = idx - rr * OUTD;
      const int y  = rlo + rr;

      // roi_align sample (aligned=True, sampling_ratio=1)
      const float ysv = sy0 + ((float)y + 0.5f) * bhv;
      const float xsv = sx0 + ((float)x + 0.5f) * bwv;
      const float valid =
          (ysv >= -1.0f && ysv <= (float)BH && xsv >= -1.0f && xsv <= (float)BW)
              ? 1.0f : 0.0f;
      const float ycc = fminf(fmaxf(ysv, 0.0f), (float)(BH - 1));
      const float xcc = fminf(fmaxf(xsv, 0.0f), (float)(BW - 1));
      int yl = (int)floorf(ycc); yl = yl > (BH - 2) ? (BH - 2) : yl;
      int xl = (int)floorf(xcc); xl = xl > (BW - 2) ? (BW - 2) : xl;
      const float ly = ycc - (float)yl, hy = 1.0f - ly;
      const float lx = xcc - (float)xl, hx = 1.0f - lx;
      const float w00 = hy * hx, w01 = hy * lx, w10 = ly * hx, w11 = ly * lx;

      // coeff 14->56 bilinear upsample coords (edge clamp)
      float cyf = fminf(fmaxf(((float)y + 0.5f) * 0.25f - 0.5f, 0.0f),
                        (float)(COD - 1));
      float cxf = fminf(fmaxf(((float)x + 0.5f) * 0.25f - 0.5f, 0.0f),
                        (float)(COD - 1));
      int cyl = (int)floorf(cyf); cyl = cyl > (COD - 2) ? (COD - 2) : cyl;
      int cxl = (int)floorf(cxf); cxl = cxl > (COD - 2) ? (COD - 2) : cxl;
      const float cly = cyf - (float)cyl, chy = 1.0f - cly;
      const float clx = cxf - (float)cxl, chx = 1.0f - clx;
      const float cw00 = chy * chx, cw01 = chy * clx;
      const float cw10 = cly * chx, cw11 = cly * clx;

      float rvals[BB], cvals[BB];
#pragma unroll
      for (int bb = 0; bb < BB; ++bb) {
        const float* fb = feat + bb * BH * BW;
        const float r =
            w00 * fb[yl * BW + xl]       + w01 * fb[yl * BW + xl + 1] +
            w10 * fb[(yl + 1) * BW + xl] + w11 * fb[(yl + 1) * BW + xl + 1];
        rvals[bb] = r * valid;
        const float* tb = top + bb * COD * COD;
        cvals[bb] =
            cw00 * tb[cyl * COD + cxl]       + cw01 * tb[cyl * COD + cxl + 1] +
            cw10 * tb[(cyl + 1) * COD + cxl] + cw11 * tb[(cyl + 1) * COD + cxl + 1];
      }

      const float mx = fmaxf(fmaxf(cvals[0], cvals[1]),
                             fmaxf(cvals[2], cvals[3]));
      float e[BB], s = 0.0f;
#pragma unroll
      for (int bb = 0; bb < BB; ++bb) { e[bb] = __expf(cvals[bb] - mx); s += e[bb]; }
      const float inv = 1.0f / s;
      float dot = 0.0f;
#pragma unroll
      for (int bb = 0; bb < BB; ++bb) dot += rvals[bb] * (e[bb] * inv);
      mrows[rr][x] = 1.0f / (1.0f + __expf(-dot));
    }
  }
  __syncthreads();

  const int q4 = q4_lo + tid;
  if (q4 >= q4_hi || q4 >= W4) return;             // after barrier: safe

  // ---- per-column bilinear x setup, reused for the band's rows ----
  int   xls[4], xhs[4];
  float wx0[4], wx1[4];
#pragma unroll
  for (int i = 0; i < 4; ++i) {
    const float q  = (float)(q4 * 4 + i);
    const float fx = fmaf(q, invw, cxo);
    const bool vx = (fx > -1.0f && fx < (float)OUTD);
    const int xl = (int)floorf(fx);
    float w1 = fx - (float)xl;
    float w0 = 1.0f - w1;
    if (xl < 0)            w0 = 0.0f;
    if (xl + 1 > OUTD - 1) w1 = 0.0f;
    int lo = xl < 0 ? 0 : xl;
    lo = lo > OUTD - 1 ? OUTD - 1 : lo;            // clamp BOTH sides
    int hi = xl + 1 < 0 ? 0 : xl + 1;
    hi = hi > OUTD - 1 ? OUTD - 1 : hi;
    xls[i] = lo; xhs[i] = hi;
    wx0[i] = vx ? w0 : 0.0f;
    wx1[i] = vx ? w1 : 0.0f;
  }

  f4* oband = out + ((size_t)n * IMGH + h0) * W4 + q4;

  // ---- paste the band's rows from LDS ----
  for (int r = 0; r < RPB; ++r) {
    const int h = h0 + r;
    if (h >= h_hi) break;                          // wave-uniform
    const float fy = fmaf((float)h, invh, cyo);
    f4 v = (f4)0.0f;
    if (fy > -1.0f && fy < (float)OUTD) {          // wave-uniform
      const int ml = (int)floorf(fy);              // -1 .. 55
      float wy1 = fy - (float)ml;
      float wy0 = 1.0f - wy1;
      if (ml < 0)            wy0 = 0.0f;
      if (ml + 1 > OUTD - 1) wy1 = 0.0f;
      int i0 = ml - rlo;
      i0 = i0 < 0 ? 0 : (i0 > nrows - 1 ? nrows - 1 : i0);
      int i1 = ml + 1 - rlo;
      i1 = i1 < 0 ? 0 : (i1 > nrows - 1 ? nrows - 1 : i1);
      const float* m0 = mrows[i0];
      const float* m1 = mrows[i1];
      float res[4];
#pragma unroll
      for (int i = 0; i < 4; ++i) {
        res[i] = wy0 * (wx0[i] * m0[xls[i]] + wx1[i] * m0[xhs[i]]) +
                 wy1 * (wx0[i] * m1[xls[i]] + wx1[i] * m1[xhs[i]]);
      }
      v = (f4){res[0], res[1], res[2], res[3]};
    }
    oband[(size_t)r * W4] = v;
  }
}

extern "C" void kernel_launch(void* const* d_in, const int* in_sizes, int n_in,
                              void* d_out, int out_size, void* d_ws, size_t ws_size,
                              hipStream_t stream) {
  const float* bases    = (const float*)d_in[0];
  const float* box_feat = (const float*)d_in[1];
  const int N = in_sizes[1] / BFS;

  // Zero the whole output via the runtime's fill path (graph memset node;
  // fillBufferAligned measured at 6.6 TB/s in this graph vs ~2.5-3 TB/s for
  // our own kernels' store streams). 174 MB -> ~26 us if it runs at fill
  // rate. Stream-ordered async op, graph-capturable (harness's own reset()
  // uses hipMemsetAsync).
  (void)hipMemsetAsync(d_out, 0, (size_t)N * IMGH * IMGW * sizeof(float),
                       stream);

  // Then paste only the interior (~3-25% of pixels per roi).
  dim3 g(MAXCH, N);
  interior_kernel<<<g, 128, 0, stream>>>(bases, box_feat, (f4*)d_out);
}

// Round 7
// 173.250 us; speedup vs baseline: 1.0397x; 1.0397x over previous
//
#include <hip/hip_runtime.h>
#include <math.h>

// Problem constants: bases [1,4,136,200] f32, box_feat [N,789] f32
// (col0 = image idx, 1:5 = box, 5: = 4*14*14 coeffs), out [N,544,800] f32.
#define OUTD 56
#define COD  14
#define BH   136
#define BW   200
#define IMGH 544
#define IMGW 800
#define BB   4
#define BFS  789      // 5 + 4*14*14
#define RPB  8        // output rows per band (544 = 68 * 8)
#define W4   (IMGW / 4)
#define MAXMR 16      // max mask rows per band: box >= 32px -> invh <= 1.75

typedef float f4 __attribute__((ext_vector_type(4)));

// ---------------------------------------------------------------------------
// FINAL: single fused kernel (round-4 design, best verified single-dispatch
// configuration). Block = (8-row band, roi); writes every output float4
// exactly once with plain stores.
//   - band outside box support -> contiguous zero store stream.
//   - interior band -> recompute the <=16 needed 56-wide mask rows into LDS
//     (roi_align + coeff-upsample + softmax + sigmoid), one __syncthreads,
//     then paste with per-column x-weights computed once, reused for 8 rows.
// Session evidence (7 measurements, 6 structural variants): non-fill time is
// invariant at 66-74 us; floor = 174 MB mandatory writes at the ~2.55 TB/s
// effective in-stream write rate (or full-rate writes + ~35-40 us fixed
// graph-replay overhead - indistinguishable, both measured AT the floor).
// Delegating zeros to hipMemsetAsync (runtime fill path) regressed: the
// runtime fill also runs ~2.5 TB/s in our stream position.
// ---------------------------------------------------------------------------
__global__ __launch_bounds__(256) void fused_kernel(
    const float* __restrict__ bases,
    const float* __restrict__ box_feat,
    f4* __restrict__ out) {
  const int n  = blockIdx.y;
  const int h0 = blockIdx.x * RPB;
  const int tid = threadIdx.x;

  const float* bf = box_feat + (size_t)n * BFS;
  const float x0 = bf[1], y0v = bf[2], x1 = bf[3], y1v = bf[4];

  const float invh = (float)OUTD / (y1v - y0v);
  const float cyo  = (0.5f - y0v) * invh - 0.5f;   // fy(h) = h*invh + cyo
  const float invw = (float)OUTD / (x1 - x0);
  const float cxo  = (0.5f - x0) * invw - 0.5f;    // fx(q) = q*invw + cxo

  const float fy_lo = fmaf((float)h0, invh, cyo);
  const float fy_hi = fmaf((float)(h0 + RPB - 1), invh, cyo);

  f4* oband = out + ((size_t)n * IMGH + h0) * W4;

  // ---- all-zero band: pure contiguous store stream ----
  if (!(fy_hi > -1.0f && fy_lo < (float)OUTD)) {   // block-uniform
    const f4 z = (f4)0.0f;
    for (int i = tid; i < RPB * W4; i += 256)
      oband[i] = z;
    return;
  }

  // ---- mask rows needed by this band (outward-safe, <= MAXMR) ----
  int rlo = (int)floorf(fy_lo);
  rlo = rlo < 0 ? 0 : (rlo > OUTD - 1 ? OUTD - 1 : rlo);
  int rhi = (int)floorf(fy_hi) + 1;
  rhi = rhi < 0 ? 0 : (rhi > OUTD - 1 ? OUTD - 1 : rhi);
  const int nrows = rhi - rlo + 1;                 // 1 .. MAXMR

  __shared__ float mrows[MAXMR][OUTD];

  // ---- mask eval into LDS ----
  {
    const int bidx = (int)bf[0];
    const float* feat = bases + (size_t)bidx * BB * BH * BW;
    const float* top  = bf + 5;
    const float sx0 = x0 * 0.25f - 0.5f;
    const float sy0 = y0v * 0.25f - 0.5f;
    const float bwv = (x1 - x0) * 0.25f * (1.0f / OUTD);
    const float bhv = (y1v - y0v) * 0.25f * (1.0f / OUTD);
    const int nev = nrows * OUTD;

    for (int idx = tid; idx < nev; idx += 256) {
      const int rr = idx / OUTD;                   // const div -> magic mul
      const int x  = idx - rr * OUTD;
      const int y  = rlo + rr;

      // roi_align sample (aligned=True, sampling_ratio=1)
      const float ysv = sy0 + ((float)y + 0.5f) * bhv;
      const float xsv = sx0 + ((float)x + 0.5f) * bwv;
      const float valid =
          (ysv >= -1.0f && ysv <= (float)BH && xsv >= -1.0f && xsv <= (float)BW)
              ? 1.0f : 0.0f;
      const float ycc = fminf(fmaxf(ysv, 0.0f), (float)(BH - 1));
      const float xcc = fminf(fmaxf(xsv, 0.0f), (float)(BW - 1));
      int yl = (int)floorf(ycc); yl = yl > (BH - 2) ? (BH - 2) : yl;
      int xl = (int)floorf(xcc); xl = xl > (BW - 2) ? (BW - 2) : xl;
      const float ly = ycc - (float)yl, hy = 1.0f - ly;
      const float lx = xcc - (float)xl, hx = 1.0f - lx;
      const float w00 = hy * hx, w01 = hy * lx, w10 = ly * hx, w11 = ly * lx;

      // coeff 14->56 bilinear upsample coords (edge clamp)
      float cyf = fminf(fmaxf(((float)y + 0.5f) * 0.25f - 0.5f, 0.0f),
                        (float)(COD - 1));
      float cxf = fminf(fmaxf(((float)x + 0.5f) * 0.25f - 0.5f, 0.0f),
                        (float)(COD - 1));
      int cyl = (int)floorf(cyf); cyl = cyl > (COD - 2) ? (COD - 2) : cyl;
      int cxl = (int)floorf(cxf); cxl = cxl > (COD - 2) ? (COD - 2) : cxl;
      const float cly = cyf - (float)cyl, chy = 1.0f - cly;
      const float clx = cxf - (float)cxl, chx = 1.0f - clx;
      const float cw00 = chy * chx, cw01 = chy * clx;
      const float cw10 = cly * chx, cw11 = cly * clx;

      float rvals[BB], cvals[BB];
#pragma unroll
      for (int bb = 0; bb < BB; ++bb) {
        const float* fb = feat + bb * BH * BW;
        const float r =
            w00 * fb[yl * BW + xl]       + w01 * fb[yl * BW + xl + 1] +
            w10 * fb[(yl + 1) * BW + xl] + w11 * fb[(yl + 1) * BW + xl + 1];
        rvals[bb] = r * valid;
        const float* tb = top + bb * COD * COD;
        cvals[bb] =
            cw00 * tb[cyl * COD + cxl]       + cw01 * tb[cyl * COD + cxl + 1] +
            cw10 * tb[(cyl + 1) * COD + cxl] + cw11 * tb[(cyl + 1) * COD + cxl + 1];
      }

      const float mx = fmaxf(fmaxf(cvals[0], cvals[1]),
                             fmaxf(cvals[2], cvals[3]));
      float e[BB], s = 0.0f;
#pragma unroll
      for (int bb = 0; bb < BB; ++bb) { e[bb] = __expf(cvals[bb] - mx); s += e[bb]; }
      const float inv = 1.0f / s;
      float dot = 0.0f;
#pragma unroll
      for (int bb = 0; bb < BB; ++bb) dot += rvals[bb] * (e[bb] * inv);
      mrows[rr][x] = 1.0f / (1.0f + __expf(-dot));
    }
  }
  __syncthreads();

  // ---- per-column bilinear x setup, computed once, reused for 8 rows ----
  const bool active = tid < W4;
  int   xls[4], xhs[4];
  float wx0[4], wx1[4];
#pragma unroll
  for (int i = 0; i < 4; ++i) {
    const float q  = (float)(tid * 4 + i);
    const float fx = fmaf(q, invw, cxo);
    const bool vx = (fx > -1.0f && fx < (float)OUTD);
    const int xl = (int)floorf(fx);
    float w1 = fx - (float)xl;
    float w0 = 1.0f - w1;
    if (xl < 0)            w0 = 0.0f;
    if (xl + 1 > OUTD - 1) w1 = 0.0f;
    int lo = xl < 0 ? 0 : xl;
    lo = lo > OUTD - 1 ? OUTD - 1 : lo;           // clamp BOTH sides
    int hi = xl + 1 < 0 ? 0 : xl + 1;
    hi = hi > OUTD - 1 ? OUTD - 1 : hi;
    xls[i] = lo; xhs[i] = hi;
    wx0[i] = vx ? w0 : 0.0f;
    wx1[i] = vx ? w1 : 0.0f;
  }

  // ---- paste the 8 rows from LDS ----
  for (int r = 0; r < RPB; ++r) {
    const float fy = fmaf((float)(h0 + r), invh, cyo);
    f4 v = (f4)0.0f;
    if (fy > -1.0f && fy < (float)OUTD) {          // wave-uniform
      const int ml = (int)floorf(fy);              // -1 .. 55
      float wy1 = fy - (float)ml;
      float wy0 = 1.0f - wy1;
      if (ml < 0)            wy0 = 0.0f;
      if (ml + 1 > OUTD - 1) wy1 = 0.0f;
      int i0 = ml - rlo;
      i0 = i0 < 0 ? 0 : (i0 > nrows - 1 ? nrows - 1 : i0);
      int i1 = ml + 1 - rlo;
      i1 = i1 < 0 ? 0 : (i1 > nrows - 1 ? nrows - 1 : i1);
      const float* m0 = mrows[i0];
      const float* m1 = mrows[i1];
      float res[4];
#pragma unroll
      for (int i = 0; i < 4; ++i) {
        res[i] = wy0 * (wx0[i] * m0[xls[i]] + wx1[i] * m0[xhs[i]]) +
                 wy1 * (wx0[i] * m1[xls[i]] + wx1[i] * m1[xhs[i]]);
      }
      v = (f4){res[0], res[1], res[2], res[3]};
    }
    if (active)
      oband[(size_t)r * W4 + tid] = v;
  }
}

extern "C" void kernel_launch(void* const* d_in, const int* in_sizes, int n_in,
                              void* d_out, int out_size, void* d_ws, size_t ws_size,
                              hipStream_t stream) {
  const float* bases    = (const float*)d_in[0];
  const float* box_feat = (const float*)d_in[1];
  const int N = in_sizes[1] / BFS;

  dim3 g(IMGH / RPB, N);   // 68 x N blocks, one dispatch total
  fused_kernel<<<g, 256, 0, stream>>>(bases, box_feat, (f4*)d_out);
}